// Round 8
// baseline (3089.451 us; speedup 1.0000x reference)
//
#include <hip/hip_runtime.h>
#include <hip/hip_bf16.h>

#define N_PTS 16384
#define DIM   128

typedef __bf16 bf16x8 __attribute__((ext_vector_type(8)));
typedef float  f32x4  __attribute__((ext_vector_type(4)));
typedef float  f32x16 __attribute__((ext_vector_type(16)));

// Monotone map float -> uint so unsigned atomicMin == float min (handles negatives).
__device__ __forceinline__ unsigned fmap(float f) {
    unsigned u = __float_as_uint(f);
    return (u & 0x80000000u) ? ~u : (u | 0x80000000u);
}
__device__ __forceinline__ float funmap(unsigned u) {
    return __uint_as_float((u & 0x80000000u) ? (u & 0x7FFFFFFFu) : ~u);
}

__device__ __forceinline__ void gload_lds16(const void* g, void* l) {
    __builtin_amdgcn_global_load_lds(
        (const __attribute__((address_space(1))) void*)g,
        (__attribute__((address_space(3))) void*)l, 16, 0, 0);
}

// B-side norm fragment for k=128..143: hi=0 lanes {b2hi,b2lo,1,1,0...}, hi=1 zeros.
__device__ __forceinline__ bf16x8 make_b2frag(unsigned p, int hi) {
    uint4 u;
    u.x = hi ? 0u : p;
    u.y = hi ? 0u : 0x3F803F80u;
    u.z = 0u; u.w = 0u;
    return __builtin_bit_cast(bf16x8, u);
}

// ---------------------------------------------------------------------------
// Prep v8: Ax[r] = bf16(-2*a[r][k]) (128), Bx[c] = bf16(b[c][k]) (128);
// norms packed as u32 (bf16 hi | bf16 lo << 16) in a2pack/b2pack.
// dot(AxRow+augA, BxRow+augB) = -2a.b + a2 + b2 = dist^2 (aug built in regs).
// Also inits the 6*N min buffer (2 row slices + 4 col slices).
// ---------------------------------------------------------------------------
__global__ void chamfer_prep8(const float* __restrict__ A, const float* __restrict__ B,
                              unsigned short* __restrict__ Ax, unsigned short* __restrict__ Bx,
                              unsigned* __restrict__ a2pack, unsigned* __restrict__ b2pack,
                              unsigned* __restrict__ minbuf) {
    int gtid = blockIdx.x * 256 + threadIdx.x;
    if (gtid < 6 * N_PTS) minbuf[gtid] = 0xFFFFFFFFu;

    int wave = blockIdx.x * 4 + (threadIdx.x >> 6);
    int lane = threadIdx.x & 63;
    int isB  = wave >= N_PTS;
    int row  = isB ? (wave - N_PTS) : wave;
    const float* src = isB ? B : A;
    unsigned short* dst = isB ? Bx : Ax;

    float2 v = *reinterpret_cast<const float2*>(&src[(size_t)row * DIM + lane * 2]);
    float sc = isB ? 1.f : -2.f;
    __bf16 bx = (__bf16)(sc * v.x), by = (__bf16)(sc * v.y);
    ushort2 st;
    st.x = __builtin_bit_cast(unsigned short, bx);
    st.y = __builtin_bit_cast(unsigned short, by);
    *reinterpret_cast<ushort2*>(&dst[(size_t)row * DIM + lane * 2]) = st;

    float s = fmaf(v.x, v.x, v.y * v.y);
    #pragma unroll
    for (int off = 1; off < 64; off <<= 1) s += __shfl_xor(s, off);

    if (lane == 0) {
        __bf16 hb = (__bf16)s;
        float  hf = (float)hb;
        __bf16 lb = (__bf16)(s - hf);
        unsigned hu = __builtin_bit_cast(unsigned short, hb);
        unsigned lu = __builtin_bit_cast(unsigned short, lb);
        (isB ? b2pack : a2pack)[row] = hu | (lu << 16);
    }
}

// ---------------------------------------------------------------------------
// GEMM+min v8: 2048 blocks x 256 threads (4 waves, 2x2), 3 blocks/CU target.
// Block b: rows [(b>>4)*128, +128), col slice (b&15): 16 tiles of 64 cols.
// A data frags in registers; norm k-step built in registers; B tile 64x128
// bf16 = 16KB double-buffered, staged via global_load_lds with pre-swizzled
// source (key = (col ^ col>>3) & 7 -> conflict-free column reads).
// 2-deep counted-vmcnt pipeline. C/D (32x32x16): col=lane&31,
// row = (reg&3)+8*(reg>>2)+4*(lane>>5).
// ---------------------------------------------------------------------------
__global__ __launch_bounds__(256, 3)
void chamfer_gemm_min8(const unsigned short* __restrict__ Ax,
                       const unsigned short* __restrict__ Bx,
                       const unsigned* __restrict__ a2pack,
                       const unsigned* __restrict__ b2pack,
                       unsigned* __restrict__ rowminS,    // [2][N_PTS]
                       unsigned* __restrict__ colminS) {  // [4][N_PTS]
    __shared__ __align__(16) unsigned char sB[2][16384];

    const int b    = blockIdx.x;
    const int tm   = (b >> 4) * 128;
    const int col0 = (b & 15) * 1024;
    const int cslc = (b >> 4) & 3;     // col-min slice

    const int t = threadIdx.x, w = t >> 6, lane = t & 63;
    const int ll = lane & 31, hi = lane >> 5;
    const int wr = (w >> 1) * 64, wc = (w & 1) * 32;

    // ---- A fragments -> registers (data ks 0..7 + register-built ks 8) ----
    bf16x8 af[2][9];
    #pragma unroll
    for (int mi = 0; mi < 2; ++mi) {
        const int row = tm + wr + mi * 32 + ll;
        const unsigned short* ap = Ax + (size_t)row * DIM + hi * 8;
        #pragma unroll
        for (int ks = 0; ks < 8; ++ks)
            af[mi][ks] = *reinterpret_cast<const bf16x8*>(ap + ks * 16);
        unsigned apk = a2pack[row];
        uint4 au;
        au.x = hi ? 0u : 0x3F803F80u;   // {1,1}
        au.y = hi ? 0u : apk;           // {a2hi,a2lo}
        au.z = 0u; au.w = 0u;
        af[mi][8] = __builtin_bit_cast(bf16x8, au);
    }

    // ---- staging source offsets (elements), 4 chunks per thread ----
    int goff[4];
    #pragma unroll
    for (int j = 0; j < 4; ++j) {
        int d = (w * 4 + j) * 64 + lane;            // linear 16B chunk 0..1023
        int c = d >> 4, s = d & 15;
        int key = (c ^ (c >> 3)) & 7;
        goff[j] = c * DIM + ((s ^ key) << 3);
    }

    // ---- LDS read base: addr(ks) = rbase ^ (ks<<5) (slot bits disjoint) ----
    const int cl    = wc + ll;
    const int rkey  = (cl ^ (cl >> 3)) & 7;
    const int rbase = cl * 256 + ((hi ^ rkey) << 4);

    // ---- prologue: stage tiles 0 and 1 ----
    const unsigned short* bq = Bx + (size_t)col0 * DIM;
    #pragma unroll
    for (int j = 0; j < 4; ++j)
        gload_lds16(bq + goff[j], &sB[0][((w * 4 + j) * 64 + lane) * 16]);
    #pragma unroll
    for (int j = 0; j < 4; ++j)
        gload_lds16(bq + 64 * DIM + goff[j], &sB[1][((w * 4 + j) * 64 + lane) * 16]);
    asm volatile("s_waitcnt vmcnt(4)" ::: "memory");   // tile 0 landed
    __builtin_amdgcn_sched_barrier(0);
    __builtin_amdgcn_s_barrier();
    __builtin_amdgcn_sched_barrier(0);

    bf16x8 b2frag = make_b2frag(b2pack[col0 + wc + ll], hi);

    float rmin_part[32];
    #pragma unroll
    for (int k = 0; k < 32; ++k) rmin_part[k] = 3.4e38f;

    #pragma unroll 2
    for (int it = 0; it < 16; ++it) {
        const unsigned char* sbC = sB[it & 1];

        // ---- MFMA: 64 rows x 32 cols per wave, 9 k-steps ----
        __builtin_amdgcn_s_setprio(1);
        f32x16 a0 = {}, a1 = {};
        #pragma unroll
        for (int ks = 0; ks < 8; ++ks) {
            bf16x8 bb = *reinterpret_cast<const bf16x8*>(sbC + (rbase ^ (ks << 5)));
            a0 = __builtin_amdgcn_mfma_f32_32x32x16_bf16(af[0][ks], bb, a0, 0, 0, 0);
            a1 = __builtin_amdgcn_mfma_f32_32x32x16_bf16(af[1][ks], bb, a1, 0, 0, 0);
        }
        a0 = __builtin_amdgcn_mfma_f32_32x32x16_bf16(af[0][8], b2frag, a0, 0, 0, 0);
        a1 = __builtin_amdgcn_mfma_f32_32x32x16_bf16(af[1][8], b2frag, a1, 0, 0, 0);
        __builtin_amdgcn_s_setprio(0);

        // ---- barrier1: all reads of this buffer retired ----
        __builtin_amdgcn_sched_barrier(0);
        __builtin_amdgcn_s_barrier();
        __builtin_amdgcn_sched_barrier(0);

        // ---- stage tile it+2 into the just-consumed buffer + next b2 ----
        if (it + 2 < 16) {
            const unsigned short* bp = bq + (size_t)(it + 2) * 64 * DIM;
            #pragma unroll
            for (int j = 0; j < 4; ++j)
                gload_lds16(bp + goff[j], &sB[it & 1][((w * 4 + j) * 64 + lane) * 16]);
        }
        unsigned pn = 0;
        if (it + 1 < 16) pn = b2pack[col0 + (it + 1) * 64 + wc + ll];

        // ---- epilogue (register VALU only) under the in-flight loads ----
        #pragma unroll
        for (int r = 0; r < 16; ++r) {
            rmin_part[r]      = fminf(rmin_part[r],      a0[r]);
            rmin_part[16 + r] = fminf(rmin_part[16 + r], a1[r]);
        }
        float cm = fminf(a0[0], a1[0]);
        #pragma unroll
        for (int r = 1; r < 16; ++r) cm = fminf(cm, fminf(a0[r], a1[r]));
        cm = fminf(cm, __shfl_xor(cm, 32));
        const int own_col = col0 + it * 64 + wc + ll;

        // ---- counted wait (never 0 in steady state) + barrier2 ----
        if (it < 14) { asm volatile("s_waitcnt vmcnt(7)" ::: "memory"); }
        else         { asm volatile("s_waitcnt vmcnt(0)" ::: "memory"); }
        __builtin_amdgcn_sched_barrier(0);
        __builtin_amdgcn_s_barrier();
        __builtin_amdgcn_sched_barrier(0);

        if (hi == 0)
            atomicMin(&colminS[(size_t)cslc * N_PTS + own_col], fmap(cm));
        b2frag = make_b2frag(pn, hi);
    }

    // ---- final row reduce-scatter: 32 vars over 32 ll-lanes, 5 stages ----
    #pragma unroll
    for (int s = 16; s >= 1; s >>= 1) {
        #pragma unroll
        for (int k = 0; k < 16; ++k) {
            if (k < s) {
                float snd = (ll & s) ? rmin_part[k] : rmin_part[k + s];
                float r = __shfl_xor(snd, s);
                rmin_part[k] = (ll & s) ? fminf(rmin_part[k + s], r) : fminf(rmin_part[k], r);
            }
        }
    }
    const int own_row = tm + wr + ((ll >> 4) << 5) + (ll & 3) + (((ll >> 2) & 3) << 3) + (hi << 2);
    atomicMin(&rowminS[(size_t)(w & 1) * N_PTS + own_row], fmap(rmin_part[0]));
}

// ---------------------------------------------------------------------------
// Finalize, two-stage: rows min over 2 slices, cols min over 4; double sums.
// ---------------------------------------------------------------------------
__global__ void chamfer_partial8(const unsigned* __restrict__ rowminS,
                                 const unsigned* __restrict__ colminS,
                                 double* __restrict__ partials) {
    __shared__ double sred[4];
    int t = threadIdx.x;
    int i = blockIdx.x * 256 + t;
    unsigned rm = min(rowminS[i], rowminS[i + N_PTS]);
    unsigned cm = min(min(colminS[i],             colminS[i + N_PTS]),
                      min(colminS[i + 2 * N_PTS], colminS[i + 3 * N_PTS]));
    double s = (double)funmap(rm) + (double)funmap(cm);
    #pragma unroll
    for (int off = 32; off; off >>= 1) s += __shfl_down(s, off);
    if ((t & 63) == 0) sred[t >> 6] = s;
    __syncthreads();
    if (t == 0) partials[blockIdx.x] = sred[0] + sred[1] + sred[2] + sred[3];
}

__global__ void chamfer_final8(const double* __restrict__ partials,
                               float* __restrict__ out) {
    int t = threadIdx.x;   // 64 threads
    double s = partials[t];
    #pragma unroll
    for (int off = 32; off; off >>= 1) s += __shfl_down(s, off);
    if (t == 0) out[0] = (float)(s * (1.0 / (double)N_PTS));
}

// ---------------------------------------------------------------------------
// Fallback path = round-3 kernels (known-passing) if ws too small.
// ---------------------------------------------------------------------------
__global__ void chamfer_prep2(const float* __restrict__ A, const float* __restrict__ B,
                              unsigned short* __restrict__ Abf, unsigned short* __restrict__ Bbf,
                              float* __restrict__ a2, float* __restrict__ b2,
                              unsigned* __restrict__ rowmin, unsigned* __restrict__ colmin) {
    int wave = blockIdx.x * 4 + (threadIdx.x >> 6);
    int lane = threadIdx.x & 63;
    int isB  = wave >= N_PTS;
    int row  = isB ? (wave - N_PTS) : wave;
    const float* src = isB ? B : A;
    unsigned short* dst = isB ? Bbf : Abf;

    float2 v = *reinterpret_cast<const float2*>(&src[(size_t)row * DIM + lane * 2]);
    __bf16 bx = (__bf16)v.x, by = (__bf16)v.y;
    ushort2 st;
    st.x = __builtin_bit_cast(unsigned short, bx);
    st.y = __builtin_bit_cast(unsigned short, by);
    *reinterpret_cast<ushort2*>(&dst[(size_t)row * DIM + lane * 2]) = st;

    float s = fmaf(v.x, v.x, v.y * v.y);
    #pragma unroll
    for (int off = 32; off; off >>= 1) s += __shfl_down(s, off);
    if (lane == 0) {
        if (isB) { b2[row] = s; colmin[row] = 0xFFFFFFFFu; }
        else     { a2[row] = s; rowmin[row] = 0xFFFFFFFFu; }
    }
}

__global__ __launch_bounds__(512, 2)
void chamfer_gemm_min3(const unsigned short* __restrict__ Abf, const unsigned short* __restrict__ Bbf,
                       const float* __restrict__ a2, const float* __restrict__ b2,
                       unsigned* __restrict__ rowmin, unsigned* __restrict__ colmin) {
    __shared__ __align__(16) unsigned char sA[65536];
    __shared__ __align__(16) unsigned char sB2[2][32768];

    const int b = blockIdx.x;
    const int tm_base = (b >> 2) * 256;
    const int tn0 = (b & 3) * 32;

    const int t = threadIdx.x;
    const int w = t >> 6, lane = t & 63;
    const int lq = lane >> 4, lr = lane & 15;
    const int wr = (w >> 1) * 64;
    const int wc = (w & 1) * 64;

    #pragma unroll
    for (int jj = 0; jj < 8; ++jj) {
        int chunk = ((w << 3) + jj) * 64 + lane;
        int r = chunk >> 4, kc = (chunk & 15) ^ (r & 7);
        gload_lds16(Abf + (size_t)(tm_base + r) * DIM + kc * 8, sA + chunk * 16);
    }
    #pragma unroll
    for (int jj = 0; jj < 4; ++jj) {
        int chunk = ((w << 2) + jj) * 64 + lane;
        int r = chunk >> 4, kc = (chunk & 15) ^ (r & 7);
        gload_lds16(Bbf + (size_t)(tn0 * 128 + r) * DIM + kc * 8, sB2[0] + chunk * 16);
    }

    float a2v[4][4];
    #pragma unroll
    for (int mi = 0; mi < 4; ++mi) {
        float4 q = *reinterpret_cast<const float4*>(&a2[tm_base + wr + mi * 16 + lq * 4]);
        a2v[mi][0] = q.x; a2v[mi][1] = q.y; a2v[mi][2] = q.z; a2v[mi][3] = q.w;
    }
    __syncthreads();

    for (int it = 0; it < 32; ++it) {
        const int cur = it & 1;
        const int tn = tn0 + it;

        if (it + 1 < 32) {
            #pragma unroll
            for (int jj = 0; jj < 4; ++jj) {
                int chunk = ((w << 2) + jj) * 64 + lane;
                int r = chunk >> 4, kc = (chunk & 15) ^ (r & 7);
                gload_lds16(Bbf + (size_t)((tn + 1) * 128 + r) * DIM + kc * 8,
                            sB2[cur ^ 1] + chunk * 16);
            }
        }

        f32x4 acc[4][4] = {};
        #pragma unroll
        for (int ks = 0; ks < 4; ++ks) {
            const int kc = ks * 4 + lq;
            bf16x8 af2[4], bfr[4];
            #pragma unroll
            for (int mi = 0; mi < 4; ++mi) {
                int r = wr + mi * 16 + lr;
                af2[mi] = *reinterpret_cast<const bf16x8*>(&sA[r * 256 + ((kc * 16) ^ ((r & 7) << 4))]);
            }
            #pragma unroll
            for (int ni = 0; ni < 4; ++ni) {
                int r = wc + ni * 16 + lr;
                bfr[ni] = *reinterpret_cast<const bf16x8*>(&sB2[cur][r * 256 + ((kc * 16) ^ ((r & 7) << 4))]);
            }
            #pragma unroll
            for (int mi = 0; mi < 4; ++mi)
                #pragma unroll
                for (int ni = 0; ni < 4; ++ni)
                    acc[mi][ni] = __builtin_amdgcn_mfma_f32_16x16x32_bf16(af2[mi], bfr[ni], acc[mi][ni], 0, 0, 0);
        }

        const int col_base = tn * 128 + wc;
        float b2v[4];
        #pragma unroll
        for (int ni = 0; ni < 4; ++ni) b2v[ni] = b2[col_base + ni * 16 + lr];

        float v[16];
        #pragma unroll
        for (int mi = 0; mi < 4; ++mi) {
            #pragma unroll
            for (int jj = 0; jj < 4; ++jj) {
                float m = fmaf(-2.f, acc[mi][0][jj], b2v[0]);
                m = fminf(m, fmaf(-2.f, acc[mi][1][jj], b2v[1]));
                m = fminf(m, fmaf(-2.f, acc[mi][2][jj], b2v[2]));
                m = fminf(m, fmaf(-2.f, acc[mi][3][jj], b2v[3]));
                v[mi * 4 + jj] = m;
            }
        }
        #pragma unroll
        for (int k = 0; k < 8; ++k) {
            float s = (lr & 8) ? v[k] : v[k + 8];
            float r = __shfl_xor(s, 8);
            v[k] = (lr & 8) ? fminf(v[k + 8], r) : fminf(v[k], r);
        }
        #pragma unroll
        for (int k = 0; k < 4; ++k) {
            float s = (lr & 4) ? v[k] : v[k + 4];
            float r = __shfl_xor(s, 4);
            v[k] = (lr & 4) ? fminf(v[k + 4], r) : fminf(v[k], r);
        }
        #pragma unroll
        for (int k = 0; k < 2; ++k) {
            float s = (lr & 2) ? v[k] : v[k + 2];
            float r = __shfl_xor(s, 2);
            v[k] = (lr & 2) ? fminf(v[k + 2], r) : fminf(v[k], r);
        }
        {
            float s = (lr & 1) ? v[0] : v[1];
            float r = __shfl_xor(s, 1);
            v[0] = (lr & 1) ? fminf(v[1], r) : fminf(v[0], r);
        }
        const int own_row = tm_base + wr + ((lr >> 2) << 4) + (lq << 2) + (lr & 3);

        float cp[4];
        #pragma unroll
        for (int ni = 0; ni < 4; ++ni) {
            float m = fmaf(-2.f, acc[0][ni][0], a2v[0][0]);
            #pragma unroll
            for (int mi = 0; mi < 4; ++mi)
                #pragma unroll
                for (int jj = 0; jj < 4; ++jj)
                    if (mi | jj) m = fminf(m, fmaf(-2.f, acc[mi][ni][jj], a2v[mi][jj]));
            cp[ni] = m;
        }
        #pragma unroll
        for (int k = 0; k < 2; ++k) {
            float s = (lane & 16) ? cp[k] : cp[k + 2];
            float r = __shfl_xor(s, 16);
            cp[k] = (lane & 16) ? fminf(cp[k + 2], r) : fminf(cp[k], r);
        }
        float cfin;
        {
            float s = (lane & 32) ? cp[0] : cp[1];
            float r = __shfl_xor(s, 32);
            cfin = (lane & 32) ? fminf(cp[1], r) : fminf(cp[0], r);
        }
        const int ni_own = ((lq & 1) << 1) | (lq >> 1);
        const int own_col = col_base + ni_own * 16 + lr;

        __syncthreads();

        atomicMin(&rowmin[own_row], fmap(v[0]));
        atomicMin(&colmin[own_col], fmap(cfin));
    }
}

__global__ void chamfer_finalize2(const unsigned* __restrict__ rowmin,
                                  const unsigned* __restrict__ colmin,
                                  const float* __restrict__ a2, const float* __restrict__ b2,
                                  float* __restrict__ out) {
    __shared__ double sred[16];
    int t = threadIdx.x;
    double s = 0.0;
    for (int i = t; i < N_PTS; i += 1024)
        s += ((double)funmap(rowmin[i]) + (double)a2[i])
           + ((double)funmap(colmin[i]) + (double)b2[i]);
    #pragma unroll
    for (int off = 32; off; off >>= 1) s += __shfl_down(s, off);
    if ((t & 63) == 0) sred[t >> 6] = s;
    __syncthreads();
    if (t == 0) {
        double tot = 0.0;
        #pragma unroll
        for (int i = 0; i < 16; ++i) tot += sred[i];
        out[0] = (float)(tot * (1.0 / (double)N_PTS));
    }
}

// ---------------------------------------------------------------------------
extern "C" void kernel_launch(void* const* d_in, const int* in_sizes, int n_in,
                              void* d_out, int out_size, void* d_ws, size_t ws_size,
                              hipStream_t stream) {
    const float* A = (const float*)d_in[0];
    const float* B = (const float*)d_in[1];
    float* out = (float*)d_out;
    char* ws = (char*)d_ws;

    const size_t MATSZ = (size_t)N_PTS * DIM * sizeof(unsigned short);  // 4 MB
    const size_t PKSZ  = (size_t)N_PTS * 4;                             // 64 KB
    const size_t need8 = 2 * MATSZ + 2 * PKSZ + 6 * PKSZ + 64 * sizeof(double);

    const size_t need3 = 2 * MATSZ + 4 * (size_t)(1 << 16);             // ~8.65 MB

    if (ws_size >= need8) {
        unsigned short* Ax = (unsigned short*)(ws);
        unsigned short* Bx = (unsigned short*)(ws + MATSZ);
        unsigned* a2pack   = (unsigned*)(ws + 2 * MATSZ);
        unsigned* b2pack   = (unsigned*)(ws + 2 * MATSZ + PKSZ);
        unsigned* minbuf   = (unsigned*)(ws + 2 * MATSZ + 2 * PKSZ);
        unsigned* rowminS  = minbuf;                     // [2][N]
        unsigned* colminS  = minbuf + 2 * N_PTS;         // [4][N]
        double*   partials = (double*)(ws + 2 * MATSZ + 8 * PKSZ);

        chamfer_prep8<<<(2 * N_PTS) / 4, 256, 0, stream>>>(A, B, Ax, Bx, a2pack, b2pack, minbuf);
        chamfer_gemm_min8<<<2048, 256, 0, stream>>>(Ax, Bx, a2pack, b2pack, rowminS, colminS);
        chamfer_partial8<<<64, 256, 0, stream>>>(rowminS, colminS, partials);
        chamfer_final8<<<1, 64, 0, stream>>>(partials, out);
    } else if (ws_size >= need3) {
        unsigned short* Abf = (unsigned short*)(ws);
        unsigned short* Bbf = (unsigned short*)(ws + MATSZ);
        float*    a2     = (float*)(ws + 2 * MATSZ);
        float*    b2     = (float*)(ws + 2 * MATSZ + (1 << 16));
        unsigned* rowmin = (unsigned*)(ws + 2 * MATSZ + (2 << 16));
        unsigned* colmin = (unsigned*)(ws + 2 * MATSZ + (3 << 16));

        chamfer_prep2<<<(2 * N_PTS) / 4, 256, 0, stream>>>(A, B, Abf, Bbf, a2, b2, rowmin, colmin);
        chamfer_gemm_min3<<<256, 512, 0, stream>>>(Abf, Bbf, a2, b2, rowmin, colmin);
        chamfer_finalize2<<<1, 1024, 0, stream>>>(rowmin, colmin, a2, b2, out);
    }
}

// Round 9
// 172.392 us; speedup vs baseline: 17.9211x; 17.9211x over previous
//
#include <hip/hip_runtime.h>
#include <hip/hip_bf16.h>

#define N_PTS 16384
#define DIM   128

typedef __bf16 bf16x8 __attribute__((ext_vector_type(8)));
typedef float  f32x4  __attribute__((ext_vector_type(4)));
typedef float  f32x16 __attribute__((ext_vector_type(16)));

// Monotone map float -> uint so unsigned atomicMin == float min (handles negatives).
__device__ __forceinline__ unsigned fmap(float f) {
    unsigned u = __float_as_uint(f);
    return (u & 0x80000000u) ? ~u : (u | 0x80000000u);
}
__device__ __forceinline__ float funmap(unsigned u) {
    return __uint_as_float((u & 0x80000000u) ? (u & 0x7FFFFFFFu) : ~u);
}

__device__ __forceinline__ void gload_lds16(const void* g, void* l) {
    __builtin_amdgcn_global_load_lds(
        (const __attribute__((address_space(1))) void*)g,
        (__attribute__((address_space(3))) void*)l, 16, 0, 0);
}

// B-side norm fragment for k=128..143: hi=0 lanes {b2hi,b2lo,1,1,0...}, hi=1 zeros.
__device__ __forceinline__ bf16x8 make_b2frag(unsigned p, int hi) {
    uint4 u;
    u.x = hi ? 0u : p;
    u.y = hi ? 0u : 0x3F803F80u;
    u.z = 0u; u.w = 0u;
    return __builtin_bit_cast(bf16x8, u);
}

// ---------------------------------------------------------------------------
// Prep v9: Ax[r] = bf16(-2*a[r][k]) (128), Bx[c] = bf16(b[c][k]) (128);
// norms packed as u32 (bf16 hi | bf16 lo << 16). Aug k-step built in regs in
// the GEMM: dot = -2a.b + a2 + b2 = dist^2 (numerics verified rounds 4-8).
// Inits the 8*N min buffer (4 row slices + 4 col slices).
// ---------------------------------------------------------------------------
__global__ void chamfer_prep9(const float* __restrict__ A, const float* __restrict__ B,
                              unsigned short* __restrict__ Ax, unsigned short* __restrict__ Bx,
                              unsigned* __restrict__ a2pack, unsigned* __restrict__ b2pack,
                              unsigned* __restrict__ minbuf) {
    int gtid = blockIdx.x * 256 + threadIdx.x;
    if (gtid < 8 * N_PTS) minbuf[gtid] = 0xFFFFFFFFu;

    int wave = blockIdx.x * 4 + (threadIdx.x >> 6);
    int lane = threadIdx.x & 63;
    int isB  = wave >= N_PTS;
    int row  = isB ? (wave - N_PTS) : wave;
    const float* src = isB ? B : A;
    unsigned short* dst = isB ? Bx : Ax;

    float2 v = *reinterpret_cast<const float2*>(&src[(size_t)row * DIM + lane * 2]);
    float sc = isB ? 1.f : -2.f;
    __bf16 bx = (__bf16)(sc * v.x), by = (__bf16)(sc * v.y);
    ushort2 st;
    st.x = __builtin_bit_cast(unsigned short, bx);
    st.y = __builtin_bit_cast(unsigned short, by);
    *reinterpret_cast<ushort2*>(&dst[(size_t)row * DIM + lane * 2]) = st;

    float s = fmaf(v.x, v.x, v.y * v.y);
    #pragma unroll
    for (int off = 1; off < 64; off <<= 1) s += __shfl_xor(s, off);

    if (lane == 0) {
        __bf16 hb = (__bf16)s;
        float  hf = (float)hb;
        __bf16 lb = (__bf16)(s - hf);
        unsigned hu = __builtin_bit_cast(unsigned short, hb);
        unsigned lu = __builtin_bit_cast(unsigned short, lb);
        (isB ? b2pack : a2pack)[row] = hu | (lu << 16);
    }
}

// ---------------------------------------------------------------------------
// GEMM+min v9: 8192 single-wave blocks, NO LDS, NO barriers, free-running.
// Block b: col group g=b&31 (512 cols; XCD b%8 owns 4 fixed 128KB B slabs),
// row band mb=b>>5 (64 rows). Wave walks 16 iters of 32 cols.
// A frags + reg-built norm k-step in registers (one-time). B frags register
// double-buffered (bA/bB), loads issued ~1 full compute-phase ahead of use.
// C/D (32x32x16): col=lane&31, row=(reg&3)+8*(reg>>2)+4*(lane>>5).
// ---------------------------------------------------------------------------
__global__ __launch_bounds__(64, 2)
void chamfer_gemm_min9(const unsigned short* __restrict__ Ax,
                       const unsigned short* __restrict__ Bx,
                       const unsigned* __restrict__ a2pack,
                       const unsigned* __restrict__ b2pack,
                       unsigned* __restrict__ rowminS,    // [4][N_PTS]
                       unsigned* __restrict__ colminS) {  // [4][N_PTS]
    const int b    = blockIdx.x;          // 8192
    const int g    = b & 31;              // col group (512 cols)
    const int mb   = b >> 5;              // row band (64 rows)
    const int tm   = mb * 64;
    const int col0 = g * 512;

    const int lane = threadIdx.x;
    const int ll = lane & 31, hi = lane >> 5;

    // ---- A fragments -> registers (data ks 0..7 + register-built ks 8) ----
    bf16x8 af[2][9];
    #pragma unroll
    for (int mi = 0; mi < 2; ++mi) {
        const int row = tm + mi * 32 + ll;
        const unsigned short* ap = Ax + (size_t)row * DIM + hi * 8;
        #pragma unroll
        for (int ks = 0; ks < 8; ++ks)
            af[mi][ks] = *reinterpret_cast<const bf16x8*>(ap + ks * 16);
        unsigned apk = a2pack[row];
        uint4 au;
        au.x = hi ? 0u : 0x3F803F80u;   // {1,1}
        au.y = hi ? 0u : apk;           // {a2hi,a2lo}
        au.z = 0u; au.w = 0u;
        af[mi][8] = __builtin_bit_cast(bf16x8, au);
    }

    // per-lane B base: col = col0 + it*32 + ll, k-offset hi*8
    const unsigned short* bq = Bx + (size_t)(col0 + ll) * DIM + hi * 8;

    float rmin_part[32];
    #pragma unroll
    for (int k = 0; k < 32; ++k) rmin_part[k] = 3.4e38f;

    bf16x8 bA[8], bB[8], b2A, b2B;

#define LOADB9(BUF, B2, IT) { \
    const unsigned short* _bp = bq + (size_t)(IT) * 32 * DIM; \
    _Pragma("unroll") \
    for (int _ks = 0; _ks < 8; ++_ks) \
        BUF[_ks] = *reinterpret_cast<const bf16x8*>(_bp + _ks * 16); \
    B2 = make_b2frag(b2pack[col0 + (IT) * 32 + ll], hi); }

#define COMPUTE9(BUF, B2, IT) { \
    __builtin_amdgcn_s_setprio(1); \
    f32x16 _a0 = {}, _a1 = {}; \
    _Pragma("unroll") \
    for (int _ks = 0; _ks < 8; ++_ks) { \
        _a0 = __builtin_amdgcn_mfma_f32_32x32x16_bf16(af[0][_ks], BUF[_ks], _a0, 0, 0, 0); \
        _a1 = __builtin_amdgcn_mfma_f32_32x32x16_bf16(af[1][_ks], BUF[_ks], _a1, 0, 0, 0); \
    } \
    _a0 = __builtin_amdgcn_mfma_f32_32x32x16_bf16(af[0][8], B2, _a0, 0, 0, 0); \
    _a1 = __builtin_amdgcn_mfma_f32_32x32x16_bf16(af[1][8], B2, _a1, 0, 0, 0); \
    __builtin_amdgcn_s_setprio(0); \
    float _cm = fminf(_a0[0], _a1[0]); \
    _Pragma("unroll") \
    for (int _r = 0; _r < 16; ++_r) { \
        rmin_part[_r]      = fminf(rmin_part[_r],      _a0[_r]); \
        rmin_part[16 + _r] = fminf(rmin_part[16 + _r], _a1[_r]); \
        if (_r) _cm = fminf(_cm, fminf(_a0[_r], _a1[_r])); \
    } \
    _cm = fminf(_cm, __shfl_xor(_cm, 32)); \
    if (hi == 0) \
        atomicMin(&colminS[(size_t)(mb & 3) * N_PTS + col0 + (IT) * 32 + ll], fmap(_cm)); }

    // ---- prologue: 2 iterations of B in flight ----
    LOADB9(bA, b2A, 0)
    LOADB9(bB, b2B, 1)

    for (int i2 = 0; i2 < 8; ++i2) {
        const int it = i2 * 2;
        COMPUTE9(bA, b2A, it)
        if (it + 2 < 16) LOADB9(bA, b2A, it + 2)
        COMPUTE9(bB, b2B, it + 1)
        if (it + 3 < 16) LOADB9(bB, b2B, it + 3)
    }
#undef LOADB9
#undef COMPUTE9

    // ---- final row reduce-scatter: 32 vars over 32 ll-lanes, 5 stages ----
    #pragma unroll
    for (int s = 16; s >= 1; s >>= 1) {
        #pragma unroll
        for (int k = 0; k < 16; ++k) {
            if (k < s) {
                float snd = (ll & s) ? rmin_part[k] : rmin_part[k + s];
                float r = __shfl_xor(snd, s);
                rmin_part[k] = (ll & s) ? fminf(rmin_part[k + s], r) : fminf(rmin_part[k], r);
            }
        }
    }
    const int own_row = tm + ((ll >> 4) << 5) + (ll & 3) + (((ll >> 2) & 3) << 3) + (hi << 2);
    atomicMin(&rowminS[(size_t)(g & 3) * N_PTS + own_row], fmap(rmin_part[0]));
}

// ---------------------------------------------------------------------------
// Finalize, two-stage: rows min over 4 slices, cols min over 4; double sums.
// ---------------------------------------------------------------------------
__global__ void chamfer_partial9(const unsigned* __restrict__ rowminS,
                                 const unsigned* __restrict__ colminS,
                                 double* __restrict__ partials) {
    __shared__ double sred[4];
    int t = threadIdx.x;
    int i = blockIdx.x * 256 + t;
    unsigned rm = min(min(rowminS[i],             rowminS[i + N_PTS]),
                      min(rowminS[i + 2 * N_PTS], rowminS[i + 3 * N_PTS]));
    unsigned cm = min(min(colminS[i],             colminS[i + N_PTS]),
                      min(colminS[i + 2 * N_PTS], colminS[i + 3 * N_PTS]));
    double s = (double)funmap(rm) + (double)funmap(cm);
    #pragma unroll
    for (int off = 32; off; off >>= 1) s += __shfl_down(s, off);
    if ((t & 63) == 0) sred[t >> 6] = s;
    __syncthreads();
    if (t == 0) partials[blockIdx.x] = sred[0] + sred[1] + sred[2] + sred[3];
}

__global__ void chamfer_final9(const double* __restrict__ partials,
                               float* __restrict__ out) {
    int t = threadIdx.x;   // 64 threads
    double s = partials[t];
    #pragma unroll
    for (int off = 32; off; off >>= 1) s += __shfl_down(s, off);
    if (t == 0) out[0] = (float)(s * (1.0 / (double)N_PTS));
}

// ---------------------------------------------------------------------------
// Fallback path = round-3 kernels (known-passing) if ws too small.
// ---------------------------------------------------------------------------
__global__ void chamfer_prep2(const float* __restrict__ A, const float* __restrict__ B,
                              unsigned short* __restrict__ Abf, unsigned short* __restrict__ Bbf,
                              float* __restrict__ a2, float* __restrict__ b2,
                              unsigned* __restrict__ rowmin, unsigned* __restrict__ colmin) {
    int wave = blockIdx.x * 4 + (threadIdx.x >> 6);
    int lane = threadIdx.x & 63;
    int isB  = wave >= N_PTS;
    int row  = isB ? (wave - N_PTS) : wave;
    const float* src = isB ? B : A;
    unsigned short* dst = isB ? Bbf : Abf;

    float2 v = *reinterpret_cast<const float2*>(&src[(size_t)row * DIM + lane * 2]);
    __bf16 bx = (__bf16)v.x, by = (__bf16)v.y;
    ushort2 st;
    st.x = __builtin_bit_cast(unsigned short, bx);
    st.y = __builtin_bit_cast(unsigned short, by);
    *reinterpret_cast<ushort2*>(&dst[(size_t)row * DIM + lane * 2]) = st;

    float s = fmaf(v.x, v.x, v.y * v.y);
    #pragma unroll
    for (int off = 32; off; off >>= 1) s += __shfl_down(s, off);
    if (lane == 0) {
        if (isB) { b2[row] = s; colmin[row] = 0xFFFFFFFFu; }
        else     { a2[row] = s; rowmin[row] = 0xFFFFFFFFu; }
    }
}

__global__ __launch_bounds__(512, 2)
void chamfer_gemm_min3(const unsigned short* __restrict__ Abf, const unsigned short* __restrict__ Bbf,
                       const float* __restrict__ a2, const float* __restrict__ b2,
                       unsigned* __restrict__ rowmin, unsigned* __restrict__ colmin) {
    __shared__ __align__(16) unsigned char sA[65536];
    __shared__ __align__(16) unsigned char sB2[2][32768];

    const int b = blockIdx.x;
    const int tm_base = (b >> 2) * 256;
    const int tn0 = (b & 3) * 32;

    const int t = threadIdx.x;
    const int w = t >> 6, lane = t & 63;
    const int lq = lane >> 4, lr = lane & 15;
    const int wr = (w >> 1) * 64;
    const int wc = (w & 1) * 64;

    #pragma unroll
    for (int jj = 0; jj < 8; ++jj) {
        int chunk = ((w << 3) + jj) * 64 + lane;
        int r = chunk >> 4, kc = (chunk & 15) ^ (r & 7);
        gload_lds16(Abf + (size_t)(tm_base + r) * DIM + kc * 8, sA + chunk * 16);
    }
    #pragma unroll
    for (int jj = 0; jj < 4; ++jj) {
        int chunk = ((w << 2) + jj) * 64 + lane;
        int r = chunk >> 4, kc = (chunk & 15) ^ (r & 7);
        gload_lds16(Bbf + (size_t)(tn0 * 128 + r) * DIM + kc * 8, sB2[0] + chunk * 16);
    }

    float a2v[4][4];
    #pragma unroll
    for (int mi = 0; mi < 4; ++mi) {
        float4 q = *reinterpret_cast<const float4*>(&a2[tm_base + wr + mi * 16 + lq * 4]);
        a2v[mi][0] = q.x; a2v[mi][1] = q.y; a2v[mi][2] = q.z; a2v[mi][3] = q.w;
    }
    __syncthreads();

    for (int it = 0; it < 32; ++it) {
        const int cur = it & 1;
        const int tn = tn0 + it;

        if (it + 1 < 32) {
            #pragma unroll
            for (int jj = 0; jj < 4; ++jj) {
                int chunk = ((w << 2) + jj) * 64 + lane;
                int r = chunk >> 4, kc = (chunk & 15) ^ (r & 7);
                gload_lds16(Bbf + (size_t)((tn + 1) * 128 + r) * DIM + kc * 8,
                            sB2[cur ^ 1] + chunk * 16);
            }
        }

        f32x4 acc[4][4] = {};
        #pragma unroll
        for (int ks = 0; ks < 4; ++ks) {
            const int kc = ks * 4 + lq;
            bf16x8 af2[4], bfr[4];
            #pragma unroll
            for (int mi = 0; mi < 4; ++mi) {
                int r = wr + mi * 16 + lr;
                af2[mi] = *reinterpret_cast<const bf16x8*>(&sA[r * 256 + ((kc * 16) ^ ((r & 7) << 4))]);
            }
            #pragma unroll
            for (int ni = 0; ni < 4; ++ni) {
                int r = wc + ni * 16 + lr;
                bfr[ni] = *reinterpret_cast<const bf16x8*>(&sB2[cur][r * 256 + ((kc * 16) ^ ((r & 7) << 4))]);
            }
            #pragma unroll
            for (int mi = 0; mi < 4; ++mi)
                #pragma unroll
                for (int ni = 0; ni < 4; ++ni)
                    acc[mi][ni] = __builtin_amdgcn_mfma_f32_16x16x32_bf16(af2[mi], bfr[ni], acc[mi][ni], 0, 0, 0);
        }

        const int col_base = tn * 128 + wc;
        float b2v[4];
        #pragma unroll
        for (int ni = 0; ni < 4; ++ni) b2v[ni] = b2[col_base + ni * 16 + lr];

        float v[16];
        #pragma unroll
        for (int mi = 0; mi < 4; ++mi) {
            #pragma unroll
            for (int jj = 0; jj < 4; ++jj) {
                float m = fmaf(-2.f, acc[mi][0][jj], b2v[0]);
                m = fminf(m, fmaf(-2.f, acc[mi][1][jj], b2v[1]));
                m = fminf(m, fmaf(-2.f, acc[mi][2][jj], b2v[2]));
                m = fminf(m, fmaf(-2.f, acc[mi][3][jj], b2v[3]));
                v[mi * 4 + jj] = m;
            }
        }
        #pragma unroll
        for (int k = 0; k < 8; ++k) {
            float s = (lr & 8) ? v[k] : v[k + 8];
            float r = __shfl_xor(s, 8);
            v[k] = (lr & 8) ? fminf(v[k + 8], r) : fminf(v[k], r);
        }
        #pragma unroll
        for (int k = 0; k < 4; ++k) {
            float s = (lr & 4) ? v[k] : v[k + 4];
            float r = __shfl_xor(s, 4);
            v[k] = (lr & 4) ? fminf(v[k + 4], r) : fminf(v[k], r);
        }
        #pragma unroll
        for (int k = 0; k < 2; ++k) {
            float s = (lr & 2) ? v[k] : v[k + 2];
            float r = __shfl_xor(s, 2);
            v[k] = (lr & 2) ? fminf(v[k + 2], r) : fminf(v[k], r);
        }
        {
            float s = (lr & 1) ? v[0] : v[1];
            float r = __shfl_xor(s, 1);
            v[0] = (lr & 1) ? fminf(v[1], r) : fminf(v[0], r);
        }
        const int own_row = tm_base + wr + ((lr >> 2) << 4) + (lq << 2) + (lr & 3);

        float cp[4];
        #pragma unroll
        for (int ni = 0; ni < 4; ++ni) {
            float m = fmaf(-2.f, acc[0][ni][0], a2v[0][0]);
            #pragma unroll
            for (int mi = 0; mi < 4; ++mi)
                #pragma unroll
                for (int jj = 0; jj < 4; ++jj)
                    if (mi | jj) m = fminf(m, fmaf(-2.f, acc[mi][ni][jj], a2v[mi][jj]));
            cp[ni] = m;
        }
        #pragma unroll
        for (int k = 0; k < 2; ++k) {
            float s = (lane & 16) ? cp[k] : cp[k + 2];
            float r = __shfl_xor(s, 16);
            cp[k] = (lane & 16) ? fminf(cp[k + 2], r) : fminf(cp[k], r);
        }
        float cfin;
        {
            float s = (lane & 32) ? cp[0] : cp[1];
            float r = __shfl_xor(s, 32);
            cfin = (lane & 32) ? fminf(cp[1], r) : fminf(cp[0], r);
        }
        const int ni_own = ((lq & 1) << 1) | (lq >> 1);
        const int own_col = col_base + ni_own * 16 + lr;

        __syncthreads();

        atomicMin(&rowmin[own_row], fmap(v[0]));
        atomicMin(&colmin[own_col], fmap(cfin));
    }
}

__global__ void chamfer_finalize2(const unsigned* __restrict__ rowmin,
                                  const unsigned* __restrict__ colmin,
                                  const float* __restrict__ a2, const float* __restrict__ b2,
                                  float* __restrict__ out) {
    __shared__ double sred[16];
    int t = threadIdx.x;
    double s = 0.0;
    for (int i = t; i < N_PTS; i += 1024)
        s += ((double)funmap(rowmin[i]) + (double)a2[i])
           + ((double)funmap(colmin[i]) + (double)b2[i]);
    #pragma unroll
    for (int off = 32; off; off >>= 1) s += __shfl_down(s, off);
    if ((t & 63) == 0) sred[t >> 6] = s;
    __syncthreads();
    if (t == 0) {
        double tot = 0.0;
        #pragma unroll
        for (int i = 0; i < 16; ++i) tot += sred[i];
        out[0] = (float)(tot * (1.0 / (double)N_PTS));
    }
}

// ---------------------------------------------------------------------------
extern "C" void kernel_launch(void* const* d_in, const int* in_sizes, int n_in,
                              void* d_out, int out_size, void* d_ws, size_t ws_size,
                              hipStream_t stream) {
    const float* A = (const float*)d_in[0];
    const float* B = (const float*)d_in[1];
    float* out = (float*)d_out;
    char* ws = (char*)d_ws;

    const size_t MATSZ = (size_t)N_PTS * DIM * sizeof(unsigned short);  // 4 MB
    const size_t PKSZ  = (size_t)N_PTS * 4;                             // 64 KB
    const size_t need9 = 2 * MATSZ + 2 * PKSZ + 8 * PKSZ + 64 * sizeof(double);

    const size_t need3 = 2 * MATSZ + 4 * (size_t)(1 << 16);             // ~8.65 MB

    if (ws_size >= need9) {
        unsigned short* Ax = (unsigned short*)(ws);
        unsigned short* Bx = (unsigned short*)(ws + MATSZ);
        unsigned* a2pack   = (unsigned*)(ws + 2 * MATSZ);
        unsigned* b2pack   = (unsigned*)(ws + 2 * MATSZ + PKSZ);
        unsigned* minbuf   = (unsigned*)(ws + 2 * MATSZ + 2 * PKSZ);
        unsigned* rowminS  = minbuf;                     // [4][N]
        unsigned* colminS  = minbuf + 4 * N_PTS;         // [4][N]
        double*   partials = (double*)(ws + 2 * MATSZ + 10 * PKSZ);

        chamfer_prep9<<<(2 * N_PTS) / 4, 256, 0, stream>>>(A, B, Ax, Bx, a2pack, b2pack, minbuf);
        chamfer_gemm_min9<<<8192, 64, 0, stream>>>(Ax, Bx, a2pack, b2pack, rowminS, colminS);
        chamfer_partial9<<<64, 256, 0, stream>>>(rowminS, colminS, partials);
        chamfer_final9<<<1, 64, 0, stream>>>(partials, out);
    } else if (ws_size >= need3) {
        unsigned short* Abf = (unsigned short*)(ws);
        unsigned short* Bbf = (unsigned short*)(ws + MATSZ);
        float*    a2     = (float*)(ws + 2 * MATSZ);
        float*    b2     = (float*)(ws + 2 * MATSZ + (1 << 16));
        unsigned* rowmin = (unsigned*)(ws + 2 * MATSZ + (2 << 16));
        unsigned* colmin = (unsigned*)(ws + 2 * MATSZ + (3 << 16));

        chamfer_prep2<<<(2 * N_PTS) / 4, 256, 0, stream>>>(A, B, Abf, Bbf, a2, b2, rowmin, colmin);
        chamfer_gemm_min3<<<256, 512, 0, stream>>>(Abf, Bbf, a2, b2, rowmin, colmin);
        chamfer_finalize2<<<1, 1024, 0, stream>>>(rowmin, colmin, a2, b2, out);
    }
}

// Round 10
// 136.187 us; speedup vs baseline: 22.6854x; 1.2658x over previous
//
#include <hip/hip_runtime.h>
#include <hip/hip_bf16.h>

#define N_PTS 16384
#define DIM   128

typedef __bf16 bf16x8 __attribute__((ext_vector_type(8)));
typedef float  f32x4  __attribute__((ext_vector_type(4)));
typedef float  f32x16 __attribute__((ext_vector_type(16)));

// Monotone map float -> uint so unsigned atomicMin == float min (handles negatives).
__device__ __forceinline__ unsigned fmap(float f) {
    unsigned u = __float_as_uint(f);
    return (u & 0x80000000u) ? ~u : (u | 0x80000000u);
}
__device__ __forceinline__ float funmap(unsigned u) {
    return __uint_as_float((u & 0x80000000u) ? (u & 0x7FFFFFFFu) : ~u);
}

__device__ __forceinline__ void gload_lds16(const void* g, void* l) {
    __builtin_amdgcn_global_load_lds(
        (const __attribute__((address_space(1))) void*)g,
        (__attribute__((address_space(3))) void*)l, 16, 0, 0);
}

// B-side norm fragment for k=128..143: hi=0 lanes {b2hi,b2lo,1,1,0...}, hi=1 zeros.
__device__ __forceinline__ bf16x8 make_b2frag(unsigned p, int hi) {
    uint4 u;
    u.x = hi ? 0u : p;
    u.y = hi ? 0u : 0x3F803F80u;
    u.z = 0u; u.w = 0u;
    return __builtin_bit_cast(bf16x8, u);
}

// ---------------------------------------------------------------------------
// Prep v10: cloud1 -> Ax row-major bf16(-2*a) (128/row);
//           cloud2 -> BxT k-chunk-major: 16B chunk c (k=8c..8c+7) of col r at
//           byte ((c*N + r)*16)  ->  coalesced B fragment loads in the GEMM.
// Norms packed as u32 (bf16 hi | lo<<16); aug k-step built in regs in GEMM:
// dot = -2a.b + a2 + b2 = dist^2 (numerics verified rounds 4-9).
// Inits the 8*N min buffer (4 row slices + 4 col slices).
// ---------------------------------------------------------------------------
__global__ void chamfer_prep10(const float* __restrict__ A, const float* __restrict__ B,
                               unsigned short* __restrict__ Ax, unsigned short* __restrict__ BxT,
                               unsigned* __restrict__ a2pack, unsigned* __restrict__ b2pack,
                               unsigned* __restrict__ minbuf) {
    int gtid = blockIdx.x * 256 + threadIdx.x;
    if (gtid < 8 * N_PTS) minbuf[gtid] = 0xFFFFFFFFu;

    int wave = blockIdx.x * 4 + (threadIdx.x >> 6);
    int lane = threadIdx.x & 63;
    int isB  = wave >= N_PTS;
    int row  = isB ? (wave - N_PTS) : wave;
    const float* src = isB ? B : A;

    float2 v = *reinterpret_cast<const float2*>(&src[(size_t)row * DIM + lane * 2]);
    float sc = isB ? 1.f : -2.f;
    __bf16 bx = (__bf16)(sc * v.x), by = (__bf16)(sc * v.y);
    ushort2 st;
    st.x = __builtin_bit_cast(unsigned short, bx);
    st.y = __builtin_bit_cast(unsigned short, by);

    if (!isB) {
        *reinterpret_cast<ushort2*>(&Ax[(size_t)row * DIM + lane * 2]) = st;
    } else {
        // element k -> chunk k>>3. Lane covers k = 2*lane, 2*lane+1:
        // chunk = lane>>2, dword slot = lane&3.
        unsigned pd = (unsigned)st.x | ((unsigned)st.y << 16);
        *reinterpret_cast<unsigned*>((char*)BxT +
            ((size_t)(lane >> 2) * N_PTS + row) * 16 + (lane & 3) * 4) = pd;
    }

    float s = fmaf(v.x, v.x, v.y * v.y);
    #pragma unroll
    for (int off = 1; off < 64; off <<= 1) s += __shfl_xor(s, off);

    if (lane == 0) {
        __bf16 hb = (__bf16)s;
        float  hf = (float)hb;
        __bf16 lb = (__bf16)(s - hf);
        unsigned hu = __builtin_bit_cast(unsigned short, hb);
        unsigned lu = __builtin_bit_cast(unsigned short, lb);
        (isB ? b2pack : a2pack)[row] = hu | (lu << 16);
    }
}

// ---------------------------------------------------------------------------
// GEMM+min v10: 8192 single-wave blocks, NO LDS, NO barriers, free-running.
// = v9 pipeline (2-deep register double-buffer, named bufs) + v6 BxT layout
// (coalesced B loads: consecutive lanes -> consecutive 16B).
// Block b: col group g=b&31 (512 cols; XCD b%8 owns 4 fixed ~150KB slabs),
// row band mb=b>>5 (64 rows). Wave walks 16 iters of 32 cols.
// C/D (32x32x16): col=lane&31, row=(reg&3)+8*(reg>>2)+4*(lane>>5).
// ---------------------------------------------------------------------------
__global__ __launch_bounds__(64, 2)
void chamfer_gemm_min10(const unsigned short* __restrict__ Ax,
                        const unsigned short* __restrict__ BxT,
                        const unsigned* __restrict__ a2pack,
                        const unsigned* __restrict__ b2pack,
                        unsigned* __restrict__ rowminS,    // [4][N_PTS]
                        unsigned* __restrict__ colminS) {  // [4][N_PTS]
    const int b    = blockIdx.x;          // 8192
    const int g    = b & 31;              // col group (512 cols)
    const int mb   = b >> 5;              // row band (64 rows)
    const int tm   = mb * 64;
    const int col0 = g * 512;

    const int lane = threadIdx.x;
    const int ll = lane & 31, hi = lane >> 5;

    // ---- A fragments -> registers (data ks 0..7 + register-built ks 8) ----
    bf16x8 af[2][9];
    #pragma unroll
    for (int mi = 0; mi < 2; ++mi) {
        const int row = tm + mi * 32 + ll;
        const unsigned short* ap = Ax + (size_t)row * DIM + hi * 8;
        #pragma unroll
        for (int ks = 0; ks < 8; ++ks)
            af[mi][ks] = *reinterpret_cast<const bf16x8*>(ap + ks * 16);
        unsigned apk = a2pack[row];
        uint4 au;
        au.x = hi ? 0u : 0x3F803F80u;   // {1,1}
        au.y = hi ? 0u : apk;           // {a2hi,a2lo}
        au.z = 0u; au.w = 0u;
        af[mi][8] = __builtin_bit_cast(bf16x8, au);
    }

    // per-lane B base (BxT): chunk (2ks+hi), col = col0 + it*32 + ll.
    // byte addr = ((2ks+hi)*N + col)*16 -> consecutive ll = consecutive 16B.
    const char* bbase = (const char*)BxT + ((size_t)hi * N_PTS + col0 + ll) * 16;
    const size_t KSTEP = (size_t)2 * N_PTS * 16;   // next k-chunk pair

    float rmin_part[32];
    #pragma unroll
    for (int k = 0; k < 32; ++k) rmin_part[k] = 3.4e38f;

    bf16x8 bA[8], bB[8], b2A, b2B;

#define LOADB10(BUF, B2, IT) { \
    const char* _bp = bbase + (size_t)(IT) * (32 * 16); \
    _Pragma("unroll") \
    for (int _ks = 0; _ks < 8; ++_ks) \
        BUF[_ks] = *reinterpret_cast<const bf16x8*>(_bp + (size_t)_ks * KSTEP); \
    B2 = make_b2frag(b2pack[col0 + (IT) * 32 + ll], hi); }

#define COMPUTE10(BUF, B2, IT) { \
    __builtin_amdgcn_s_setprio(1); \
    f32x16 _a0 = {}, _a1 = {}; \
    _Pragma("unroll") \
    for (int _ks = 0; _ks < 8; ++_ks) { \
        _a0 = __builtin_amdgcn_mfma_f32_32x32x16_bf16(af[0][_ks], BUF[_ks], _a0, 0, 0, 0); \
        _a1 = __builtin_amdgcn_mfma_f32_32x32x16_bf16(af[1][_ks], BUF[_ks], _a1, 0, 0, 0); \
    } \
    _a0 = __builtin_amdgcn_mfma_f32_32x32x16_bf16(af[0][8], B2, _a0, 0, 0, 0); \
    _a1 = __builtin_amdgcn_mfma_f32_32x32x16_bf16(af[1][8], B2, _a1, 0, 0, 0); \
    __builtin_amdgcn_s_setprio(0); \
    float _cm = fminf(_a0[0], _a1[0]); \
    _Pragma("unroll") \
    for (int _r = 0; _r < 16; ++_r) { \
        rmin_part[_r]      = fminf(rmin_part[_r],      _a0[_r]); \
        rmin_part[16 + _r] = fminf(rmin_part[16 + _r], _a1[_r]); \
        if (_r) _cm = fminf(_cm, fminf(_a0[_r], _a1[_r])); \
    } \
    _cm = fminf(_cm, __shfl_xor(_cm, 32)); \
    if (hi == 0) \
        atomicMin(&colminS[(size_t)(mb & 3) * N_PTS + col0 + (IT) * 32 + ll], fmap(_cm)); }

    // ---- prologue: 2 iterations of B in flight ----
    LOADB10(bA, b2A, 0)
    LOADB10(bB, b2B, 1)

    for (int i2 = 0; i2 < 8; ++i2) {
        const int it = i2 * 2;
        COMPUTE10(bA, b2A, it)
        if (it + 2 < 16) LOADB10(bA, b2A, it + 2)
        COMPUTE10(bB, b2B, it + 1)
        if (it + 3 < 16) LOADB10(bB, b2B, it + 3)
    }
#undef LOADB10
#undef COMPUTE10

    // ---- final row reduce-scatter: 32 vars over 32 ll-lanes, 5 stages ----
    #pragma unroll
    for (int s = 16; s >= 1; s >>= 1) {
        #pragma unroll
        for (int k = 0; k < 16; ++k) {
            if (k < s) {
                float snd = (ll & s) ? rmin_part[k] : rmin_part[k + s];
                float r = __shfl_xor(snd, s);
                rmin_part[k] = (ll & s) ? fminf(rmin_part[k + s], r) : fminf(rmin_part[k], r);
            }
        }
    }
    const int own_row = tm + ((ll >> 4) << 5) + (ll & 3) + (((ll >> 2) & 3) << 3) + (hi << 2);
    atomicMin(&rowminS[(size_t)(g & 3) * N_PTS + own_row], fmap(rmin_part[0]));
}

// ---------------------------------------------------------------------------
// Finalize, two-stage: rows min over 4 slices, cols min over 4; double sums.
// ---------------------------------------------------------------------------
__global__ void chamfer_partial10(const unsigned* __restrict__ rowminS,
                                  const unsigned* __restrict__ colminS,
                                  double* __restrict__ partials) {
    __shared__ double sred[4];
    int t = threadIdx.x;
    int i = blockIdx.x * 256 + t;
    unsigned rm = min(min(rowminS[i],             rowminS[i + N_PTS]),
                      min(rowminS[i + 2 * N_PTS], rowminS[i + 3 * N_PTS]));
    unsigned cm = min(min(colminS[i],             colminS[i + N_PTS]),
                      min(colminS[i + 2 * N_PTS], colminS[i + 3 * N_PTS]));
    double s = (double)funmap(rm) + (double)funmap(cm);
    #pragma unroll
    for (int off = 32; off; off >>= 1) s += __shfl_down(s, off);
    if ((t & 63) == 0) sred[t >> 6] = s;
    __syncthreads();
    if (t == 0) partials[blockIdx.x] = sred[0] + sred[1] + sred[2] + sred[3];
}

__global__ void chamfer_final10(const double* __restrict__ partials,
                                float* __restrict__ out) {
    int t = threadIdx.x;   // 64 threads
    double s = partials[t];
    #pragma unroll
    for (int off = 32; off; off >>= 1) s += __shfl_down(s, off);
    if (t == 0) out[0] = (float)(s * (1.0 / (double)N_PTS));
}

// ---------------------------------------------------------------------------
// Fallback path = round-3 kernels (known-passing) if ws too small.
// ---------------------------------------------------------------------------
__global__ void chamfer_prep2(const float* __restrict__ A, const float* __restrict__ B,
                              unsigned short* __restrict__ Abf, unsigned short* __restrict__ Bbf,
                              float* __restrict__ a2, float* __restrict__ b2,
                              unsigned* __restrict__ rowmin, unsigned* __restrict__ colmin) {
    int wave = blockIdx.x * 4 + (threadIdx.x >> 6);
    int lane = threadIdx.x & 63;
    int isB  = wave >= N_PTS;
    int row  = isB ? (wave - N_PTS) : wave;
    const float* src = isB ? B : A;
    unsigned short* dst = isB ? Bbf : Abf;

    float2 v = *reinterpret_cast<const float2*>(&src[(size_t)row * DIM + lane * 2]);
    __bf16 bx = (__bf16)v.x, by = (__bf16)v.y;
    ushort2 st;
    st.x = __builtin_bit_cast(unsigned short, bx);
    st.y = __builtin_bit_cast(unsigned short, by);
    *reinterpret_cast<ushort2*>(&dst[(size_t)row * DIM + lane * 2]) = st;

    float s = fmaf(v.x, v.x, v.y * v.y);
    #pragma unroll
    for (int off = 32; off; off >>= 1) s += __shfl_down(s, off);
    if (lane == 0) {
        if (isB) { b2[row] = s; colmin[row] = 0xFFFFFFFFu; }
        else     { a2[row] = s; rowmin[row] = 0xFFFFFFFFu; }
    }
}

__global__ __launch_bounds__(512, 2)
void chamfer_gemm_min3(const unsigned short* __restrict__ Abf, const unsigned short* __restrict__ Bbf,
                       const float* __restrict__ a2, const float* __restrict__ b2,
                       unsigned* __restrict__ rowmin, unsigned* __restrict__ colmin) {
    __shared__ __align__(16) unsigned char sA[65536];
    __shared__ __align__(16) unsigned char sB2[2][32768];

    const int b = blockIdx.x;
    const int tm_base = (b >> 2) * 256;
    const int tn0 = (b & 3) * 32;

    const int t = threadIdx.x;
    const int w = t >> 6, lane = t & 63;
    const int lq = lane >> 4, lr = lane & 15;
    const int wr = (w >> 1) * 64;
    const int wc = (w & 1) * 64;

    #pragma unroll
    for (int jj = 0; jj < 8; ++jj) {
        int chunk = ((w << 3) + jj) * 64 + lane;
        int r = chunk >> 4, kc = (chunk & 15) ^ (r & 7);
        gload_lds16(Abf + (size_t)(tm_base + r) * DIM + kc * 8, sA + chunk * 16);
    }
    #pragma unroll
    for (int jj = 0; jj < 4; ++jj) {
        int chunk = ((w << 2) + jj) * 64 + lane;
        int r = chunk >> 4, kc = (chunk & 15) ^ (r & 7);
        gload_lds16(Bbf + (size_t)(tn0 * 128 + r) * DIM + kc * 8, sB2[0] + chunk * 16);
    }

    float a2v[4][4];
    #pragma unroll
    for (int mi = 0; mi < 4; ++mi) {
        float4 q = *reinterpret_cast<const float4*>(&a2[tm_base + wr + mi * 16 + lq * 4]);
        a2v[mi][0] = q.x; a2v[mi][1] = q.y; a2v[mi][2] = q.z; a2v[mi][3] = q.w;
    }
    __syncthreads();

    for (int it = 0; it < 32; ++it) {
        const int cur = it & 1;
        const int tn = tn0 + it;

        if (it + 1 < 32) {
            #pragma unroll
            for (int jj = 0; jj < 4; ++jj) {
                int chunk = ((w << 2) + jj) * 64 + lane;
                int r = chunk >> 4, kc = (chunk & 15) ^ (r & 7);
                gload_lds16(Bbf + (size_t)((tn + 1) * 128 + r) * DIM + kc * 8,
                            sB2[cur ^ 1] + chunk * 16);
            }
        }

        f32x4 acc[4][4] = {};
        #pragma unroll
        for (int ks = 0; ks < 4; ++ks) {
            const int kc = ks * 4 + lq;
            bf16x8 af2[4], bfr[4];
            #pragma unroll
            for (int mi = 0; mi < 4; ++mi) {
                int r = wr + mi * 16 + lr;
                af2[mi] = *reinterpret_cast<const bf16x8*>(&sA[r * 256 + ((kc * 16) ^ ((r & 7) << 4))]);
            }
            #pragma unroll
            for (int ni = 0; ni < 4; ++ni) {
                int r = wc + ni * 16 + lr;
                bfr[ni] = *reinterpret_cast<const bf16x8*>(&sB2[cur][r * 256 + ((kc * 16) ^ ((r & 7) << 4))]);
            }
            #pragma unroll
            for (int mi = 0; mi < 4; ++mi)
                #pragma unroll
                for (int ni = 0; ni < 4; ++ni)
                    acc[mi][ni] = __builtin_amdgcn_mfma_f32_16x16x32_bf16(af2[mi], bfr[ni], acc[mi][ni], 0, 0, 0);
        }

        const int col_base = tn * 128 + wc;
        float b2v[4];
        #pragma unroll
        for (int ni = 0; ni < 4; ++ni) b2v[ni] = b2[col_base + ni * 16 + lr];

        float v[16];
        #pragma unroll
        for (int mi = 0; mi < 4; ++mi) {
            #pragma unroll
            for (int jj = 0; jj < 4; ++jj) {
                float m = fmaf(-2.f, acc[mi][0][jj], b2v[0]);
                m = fminf(m, fmaf(-2.f, acc[mi][1][jj], b2v[1]));
                m = fminf(m, fmaf(-2.f, acc[mi][2][jj], b2v[2]));
                m = fminf(m, fmaf(-2.f, acc[mi][3][jj], b2v[3]));
                v[mi * 4 + jj] = m;
            }
        }
        #pragma unroll
        for (int k = 0; k < 8; ++k) {
            float s = (lr & 8) ? v[k] : v[k + 8];
            float r = __shfl_xor(s, 8);
            v[k] = (lr & 8) ? fminf(v[k + 8], r) : fminf(v[k], r);
        }
        #pragma unroll
        for (int k = 0; k < 4; ++k) {
            float s = (lr & 4) ? v[k] : v[k + 4];
            float r = __shfl_xor(s, 4);
            v[k] = (lr & 4) ? fminf(v[k + 4], r) : fminf(v[k], r);
        }
        #pragma unroll
        for (int k = 0; k < 2; ++k) {
            float s = (lr & 2) ? v[k] : v[k + 2];
            float r = __shfl_xor(s, 2);
            v[k] = (lr & 2) ? fminf(v[k + 2], r) : fminf(v[k], r);
        }
        {
            float s = (lr & 1) ? v[0] : v[1];
            float r = __shfl_xor(s, 1);
            v[0] = (lr & 1) ? fminf(v[1], r) : fminf(v[0], r);
        }
        const int own_row = tm_base + wr + ((lr >> 2) << 4) + (lq << 2) + (lr & 3);

        float cp[4];
        #pragma unroll
        for (int ni = 0; ni < 4; ++ni) {
            float m = fmaf(-2.f, acc[0][ni][0], a2v[0][0]);
            #pragma unroll
            for (int mi = 0; mi < 4; ++mi)
                #pragma unroll
                for (int jj = 0; jj < 4; ++jj)
                    if (mi | jj) m = fminf(m, fmaf(-2.f, acc[mi][ni][jj], a2v[mi][jj]));
            cp[ni] = m;
        }
        #pragma unroll
        for (int k = 0; k < 2; ++k) {
            float s = (lane & 16) ? cp[k] : cp[k + 2];
            float r = __shfl_xor(s, 16);
            cp[k] = (lane & 16) ? fminf(cp[k + 2], r) : fminf(cp[k], r);
        }
        float cfin;
        {
            float s = (lane & 32) ? cp[0] : cp[1];
            float r = __shfl_xor(s, 32);
            cfin = (lane & 32) ? fminf(cp[1], r) : fminf(cp[0], r);
        }
        const int ni_own = ((lq & 1) << 1) | (lq >> 1);
        const int own_col = col_base + ni_own * 16 + lr;

        __syncthreads();

        atomicMin(&rowmin[own_row], fmap(v[0]));
        atomicMin(&colmin[own_col], fmap(cfin));
    }
}

__global__ void chamfer_finalize2(const unsigned* __restrict__ rowmin,
                                  const unsigned* __restrict__ colmin,
                                  const float* __restrict__ a2, const float* __restrict__ b2,
                                  float* __restrict__ out) {
    __shared__ double sred[16];
    int t = threadIdx.x;
    double s = 0.0;
    for (int i = t; i < N_PTS; i += 1024)
        s += ((double)funmap(rowmin[i]) + (double)a2[i])
           + ((double)funmap(colmin[i]) + (double)b2[i]);
    #pragma unroll
    for (int off = 32; off; off >>= 1) s += __shfl_down(s, off);
    if ((t & 63) == 0) sred[t >> 6] = s;
    __syncthreads();
    if (t == 0) {
        double tot = 0.0;
        #pragma unroll
        for (int i = 0; i < 16; ++i) tot += sred[i];
        out[0] = (float)(tot * (1.0 / (double)N_PTS));
    }
}

// ---------------------------------------------------------------------------
extern "C" void kernel_launch(void* const* d_in, const int* in_sizes, int n_in,
                              void* d_out, int out_size, void* d_ws, size_t ws_size,
                              hipStream_t stream) {
    const float* A = (const float*)d_in[0];
    const float* B = (const float*)d_in[1];
    float* out = (float*)d_out;
    char* ws = (char*)d_ws;

    const size_t MATSZ  = (size_t)N_PTS * DIM * sizeof(unsigned short);  // 4 MB
    const size_t PKSZ   = (size_t)N_PTS * 4;                             // 64 KB
    const size_t need10 = 2 * MATSZ + 2 * PKSZ + 8 * PKSZ + 64 * sizeof(double);

    const size_t need3  = 2 * MATSZ + 4 * (size_t)(1 << 16);             // ~8.65 MB

    if (ws_size >= need10) {
        unsigned short* Ax  = (unsigned short*)(ws);
        unsigned short* BxT = (unsigned short*)(ws + MATSZ);
        unsigned* a2pack    = (unsigned*)(ws + 2 * MATSZ);
        unsigned* b2pack    = (unsigned*)(ws + 2 * MATSZ + PKSZ);
        unsigned* minbuf    = (unsigned*)(ws + 2 * MATSZ + 2 * PKSZ);
        unsigned* rowminS   = minbuf;                     // [4][N]
        unsigned* colminS   = minbuf + 4 * N_PTS;         // [4][N]
        double*   partials  = (double*)(ws + 2 * MATSZ + 10 * PKSZ);

        chamfer_prep10<<<(2 * N_PTS) / 4, 256, 0, stream>>>(A, B, Ax, BxT, a2pack, b2pack, minbuf);
        chamfer_gemm_min10<<<8192, 64, 0, stream>>>(Ax, BxT, a2pack, b2pack, rowminS, colminS);
        chamfer_partial10<<<64, 256, 0, stream>>>(rowminS, colminS, partials);
        chamfer_final10<<<1, 64, 0, stream>>>(partials, out);
    } else if (ws_size >= need3) {
        unsigned short* Abf = (unsigned short*)(ws);
        unsigned short* Bbf = (unsigned short*)(ws + MATSZ);
        float*    a2     = (float*)(ws + 2 * MATSZ);
        float*    b2     = (float*)(ws + 2 * MATSZ + (1 << 16));
        unsigned* rowmin = (unsigned*)(ws + 2 * MATSZ + (2 << 16));
        unsigned* colmin = (unsigned*)(ws + 2 * MATSZ + (3 << 16));

        chamfer_prep2<<<(2 * N_PTS) / 4, 256, 0, stream>>>(A, B, Abf, Bbf, a2, b2, rowmin, colmin);
        chamfer_gemm_min3<<<256, 512, 0, stream>>>(Abf, Bbf, a2, b2, rowmin, colmin);
        chamfer_finalize2<<<1, 1024, 0, stream>>>(rowmin, colmin, a2, b2, out);
    }
}